// Round 1
// baseline (1249.012 us; speedup 1.0000x reference)
//
#include <hip/hip_runtime.h>
#include <cstdint>

#define T_LEN 1000
#define NB    256

__device__ __forceinline__ float rcpf_(float x)     { return __builtin_amdgcn_rcpf(x); }
__device__ __forceinline__ float sigmoidf_(float x) { return rcpf_(1.f + __expf(-x)); }
__device__ __forceinline__ float tanhf_(float x) {
    float e = __expf(2.f * x);
    return 1.f - 2.f * rcpf_(e + 1.f);
}
__device__ __forceinline__ float softplusf_(float x) {
    return fmaxf(x, 0.f) + __logf(1.f + __expf(-fabsf(x)));
}

// ---------------- K1: gi2 = mini_batch @ W_ih2^T + b_ih2  -> out[b,t,0:30] (scratch) ---------
__global__ __launch_bounds__(256) void gi2_kernel(
    const float* __restrict__ x, const float* __restrict__ W,
    const float* __restrict__ bias, float* __restrict__ out)
{
    const int lane = threadIdx.x & 63;
    const int wv   = threadIdx.x >> 6;          // 0..3, each wave covers 8 output cols
    const int64_t row = (int64_t)blockIdx.x * 64 + lane;   // one (b,t) row per lane
    const int j0 = wv * 8;
    const float* xr = x + row * 100;

    float acc[8];
#pragma unroll
    for (int jj = 0; jj < 8; ++jj) acc[jj] = 0.f;

    for (int k0 = 0; k0 < 100; k0 += 4) {
        float4 xv = *(const float4*)(xr + k0);
#pragma unroll
        for (int jj = 0; jj < 8; ++jj) {
            int j = j0 + jj; j = j > 29 ? 29 : j;      // clamp (redundant compute, guarded store)
            const float* wr = W + j * 100 + k0;        // uniform per wave -> broadcast loads
            acc[jj] = fmaf(xv.x, wr[0], acc[jj]);
            acc[jj] = fmaf(xv.y, wr[1], acc[jj]);
            acc[jj] = fmaf(xv.z, wr[2], acc[jj]);
            acc[jj] = fmaf(xv.w, wr[3], acc[jj]);
        }
    }
    float* orow = out + row * 100;
#pragma unroll
    for (int jj = 0; jj < 8; ++jj) {
        int j = j0 + jj;
        if (j < 30) orow[j] = acc[jj] + bias[j];
    }
}

// ---------------- K2: sequential scan. 1 block / batch element, 2 waves ----------------------
// wave0: h1 critical chain.  wave1: h2 GRU + emitter (lagged 1 step) + stores.
__global__ __launch_bounds__(128) void scan_kernel(
    const float* __restrict__ eps,
    const float* __restrict__ W_ih1, const float* __restrict__ W_hh1,
    const float* __restrict__ b_ih1, const float* __restrict__ b_hh1,
    const float* __restrict__ W_hh2, const float* __restrict__ b_hh2,
    const float* __restrict__ h1_0,  const float* __restrict__ h2_0,
    const float* __restrict__ Wt1,   const float* __restrict__ bt1,
    const float* __restrict__ Wloc,  const float* __restrict__ bloc,
    const float* __restrict__ Wsc,   const float* __restrict__ bsc,
    const float* __restrict__ We1,   const float* __restrict__ be1,
    const float* __restrict__ We2,   const float* __restrict__ be2,
    const float* __restrict__ We3,   const float* __restrict__ be3,
    float* out)
{
    __shared__ __align__(16) float seps[104];        // eps(t), written by wave0
    __shared__ __align__(16) float shid[20];         // hid(t), wave0 only
    __shared__ __align__(16) float ss2[2][52];       // z halves (padded), wave0 only
    __shared__ __align__(16) float sh1ring[2][12];   // h1 after step t -> slot t&1
    __shared__ __align__(16) float sh2ring[4][12];   // H2(u) -> slot u&3, wave1 only
    __shared__ __align__(16) float se1[20];          // emitter hidden 1, wave1 only
    __shared__ __align__(16) float se2[20];          // emitter hidden 2, wave1 only

    const int lane = threadIdx.x & 63;
    const int64_t rowbase = (int64_t)blockIdx.x * T_LEN * 100;
    const int wave = __builtin_amdgcn_readfirstlane((int)(threadIdx.x >> 6));

    if (wave == 0) {
        // ================= wave0: h1 chain =================
        const int j  = lane & 31;      // output index for gi1 (both halves)
        const int h  = lane >> 5;      // k-half for the 100-deep gi1 reduction
        const bool aj = (j < 30);

        float wt1r[10]; float bt1r = 0.f;
#pragma unroll
        for (int k = 0; k < 10; ++k) wt1r[k] = 0.f;
        if (lane < 20) {
#pragma unroll
            for (int k = 0; k < 10; ++k) wt1r[k] = Wt1[lane * 10 + k];
            bt1r = bt1[lane];
        }

        float whh1r[10]; float bhh1r = 0.f, br1 = 0.f;
#pragma unroll
        for (int k = 0; k < 10; ++k) whh1r[k] = 0.f;
        if (aj) {
#pragma unroll
            for (int k = 0; k < 10; ++k) whh1r[k] = W_hh1[j * 10 + k];
            bhh1r = b_hh1[j];
            br1   = b_ih1[j];
        }

        float wscA[20], wscB[20], wlocA[20], wlocB[20];
        float bscA = 0.f, bscB = 0.f, blocA = 0.f, blocB = 0.f;
#pragma unroll
        for (int l = 0; l < 20; ++l) { wscA[l] = 0.f; wscB[l] = 0.f; wlocA[l] = 0.f; wlocB[l] = 0.f; }
        if (lane < 50) {
#pragma unroll
            for (int l = 0; l < 20; ++l) {
                wscA[l]  = Wsc [ lane       * 20 + l];
                wscB[l]  = Wsc [(lane + 50) * 20 + l];
                wlocA[l] = Wloc[ lane       * 20 + l];
                wlocB[l] = Wloc[(lane + 50) * 20 + l];
            }
            bscA  = bsc [lane]; bscB  = bsc [lane + 50];
            blocA = bloc[lane]; blocB = bloc[lane + 50];
        }

        float wbig[52];
#pragma unroll
        for (int i = 0; i < 52; ++i) wbig[i] = 0.f;
        if (aj) {
#pragma unroll
            for (int i = 0; i < 50; ++i) wbig[i] = W_ih1[j * 100 + h * 50 + i];
        }

        if (lane < 10) sh1ring[1][lane] = h1_0[lane];           // slot (0-1)&1
        if (lane < 2)  { ss2[0][50 + lane] = 0.f; ss2[1][50 + lane] = 0.f; }  // zero pads

        float4 epsreg = make_float4(0.f, 0.f, 0.f, 0.f);
        if (lane < 25) epsreg = *(const float4*)(eps + rowbase + 4 * lane);   // prefetch t=0

        for (int t = 0; t <= T_LEN; ++t) {
            if (t < T_LEN) {
                // S0: publish eps(t), prefetch eps(t+1)
                if (lane < 25) {
                    *(float4*)(&seps[4 * lane]) = epsreg;
                    if (t + 1 < T_LEN)
                        epsreg = *(const float4*)(eps + rowbase + (int64_t)(t + 1) * 100 + 4 * lane);
                }

                // S1: read h1(t-1); hid = relu(Wt1 h1 + bt1); gh1 = W_hh1 h1 + b_hh1
                const int rs = (t + 1) & 1;   // == (t-1)&1
                float4 a0 = *(const float4*)(&sh1ring[rs][0]);
                float4 a1 = *(const float4*)(&sh1ring[rs][4]);
                float h18 = sh1ring[rs][8];
                float h19 = sh1ring[rs][9];
                float h1own = sh1ring[rs][lane < 10 ? lane : 0];
                float h1r[10] = {a0.x, a0.y, a0.z, a0.w, a1.x, a1.y, a1.z, a1.w, h18, h19};

                float hidv = bt1r;
#pragma unroll
                for (int k = 0; k < 10; ++k) hidv = fmaf(wt1r[k], h1r[k], hidv);
                hidv = fmaxf(hidv, 0.f);
                if (lane < 20) shid[lane] = hidv;

                float gh1v = bhh1r;
#pragma unroll
                for (int k = 0; k < 10; ++k) gh1v = fmaf(whh1r[k], h1r[k], gh1v);

                __builtin_amdgcn_wave_barrier();

                // S2: z[k] = (Wloc hid + bloc)[k] + softplus((Wsc hid + bsc)[k]) * eps[k]
                float hr[20];
                {
                    float4 b0 = *(const float4*)(&shid[0]);
                    float4 b1 = *(const float4*)(&shid[4]);
                    float4 b2 = *(const float4*)(&shid[8]);
                    float4 b3 = *(const float4*)(&shid[12]);
                    float4 b4 = *(const float4*)(&shid[16]);
                    hr[0]=b0.x; hr[1]=b0.y; hr[2]=b0.z; hr[3]=b0.w;
                    hr[4]=b1.x; hr[5]=b1.y; hr[6]=b1.z; hr[7]=b1.w;
                    hr[8]=b2.x; hr[9]=b2.y; hr[10]=b2.z; hr[11]=b2.w;
                    hr[12]=b3.x; hr[13]=b3.y; hr[14]=b3.z; hr[15]=b3.w;
                    hr[16]=b4.x; hr[17]=b4.y; hr[18]=b4.z; hr[19]=b4.w;
                }
                const int le = lane < 50 ? lane : 0;
                float e0  = seps[le];
                float e1v = seps[le + 50];
                float scA = bscA, scB = bscB, zlA = blocA, zlB = blocB;
#pragma unroll
                for (int l = 0; l < 20; ++l) {
                    scA = fmaf(wscA[l], hr[l], scA);
                    scB = fmaf(wscB[l], hr[l], scB);
                    zlA = fmaf(wlocA[l], hr[l], zlA);
                    zlB = fmaf(wlocB[l], hr[l], zlB);
                }
                float zA = fmaf(softplusf_(scA), e0,  zlA);
                float zB = fmaf(softplusf_(scB), e1v, zlB);
                if (lane < 50) { ss2[0][lane] = zA; ss2[1][lane] = zB; }

                __builtin_amdgcn_wave_barrier();

                // S3: gi1[j] = b_ih1[j] + sum_k W_ih1[j,k] z[k]  (j x k-half over 64 lanes)
                const float4* sp = (const float4*)(&ss2[h][0]);
                float p = 0.f;
#pragma unroll
                for (int c = 0; c < 13; ++c) {
                    float4 v = sp[c];
                    p = fmaf(wbig[4*c+0], v.x, p);
                    p = fmaf(wbig[4*c+1], v.y, p);
                    p = fmaf(wbig[4*c+2], v.z, p);
                    p = fmaf(wbig[4*c+3], v.w, p);
                }
                float po   = __shfl_xor(p, 32);
                float gi1v = p + po + br1;
                float av   = gi1v + gh1v;
                float a10  = __shfl(av,   lane + 10);
                float ginv = __shfl(gi1v, lane + 20);
                float ghnv = __shfl(gh1v, lane + 20);
                if (lane < 10) {
                    float r = sigmoidf_(av);
                    float u = sigmoidf_(a10);
                    float n = tanhf_(fmaf(r, ghnv, ginv));
                    float h1n = fmaf(u, h1own - n, n);   // (1-u)*n + u*h1
                    sh1ring[t & 1][lane] = h1n;
                }
            }
            __syncthreads();
        }
    } else {
        // ================= wave1: h2 chain + emitter(t-1) =================
        float whh2r[10]; float bhh2r = 0.f;
#pragma unroll
        for (int k = 0; k < 10; ++k) whh2r[k] = 0.f;
        if (lane < 30) {
#pragma unroll
            for (int k = 0; k < 10; ++k) whh2r[k] = W_hh2[lane * 10 + k];
            bhh2r = b_hh2[lane];
        }
        float we1r[20], we2r[20]; float be1r = 0.f, be2r = 0.f;
#pragma unroll
        for (int k = 0; k < 20; ++k) { we1r[k] = 0.f; we2r[k] = 0.f; }
        if (lane < 20) {
#pragma unroll
            for (int k = 0; k < 20; ++k) {
                we1r[k] = We1[lane * 20 + k];
                we2r[k] = We2[lane * 20 + k];
            }
            be1r = be1[lane]; be2r = be2[lane];
        }
        float we3A[20], we3B[20]; float be3A = 0.f, be3B = 0.f;
#pragma unroll
        for (int l = 0; l < 20; ++l) { we3A[l] = 0.f; we3B[l] = 0.f; }
        if (lane < 50) {
#pragma unroll
            for (int l = 0; l < 20; ++l) {
                we3A[l] = We3[ lane       * 20 + l];
                we3B[l] = We3[(lane + 50) * 20 + l];
            }
            be3A = be3[lane]; be3B = be3[lane + 50];
        }

        if (lane < 10) sh2ring[0][lane] = h2_0[lane];   // H2(0)

        float gi2reg = 0.f;
        if (lane < 30) gi2reg = out[rowbase + lane];    // prefetch gi2(0)

        for (int t = 0; t <= T_LEN; ++t) {
            if (t < T_LEN) {
                // h2: H2(t) -> H2(t+1) using gi2(t)
                const int rsl = t & 3;
                float4 c0v = *(const float4*)(&sh2ring[rsl][0]);
                float4 c1v = *(const float4*)(&sh2ring[rsl][4]);
                float h28 = sh2ring[rsl][8];
                float h29 = sh2ring[rsl][9];
                float h2own = sh2ring[rsl][lane < 10 ? lane : 0];
                float h2r[10] = {c0v.x,c0v.y,c0v.z,c0v.w,c1v.x,c1v.y,c1v.z,c1v.w,h28,h29};

                float gi2v = gi2reg;
                if (lane < 30 && t + 1 < T_LEN)
                    gi2reg = out[rowbase + (int64_t)(t + 1) * 100 + lane];

                float gh2v = bhh2r;
#pragma unroll
                for (int k = 0; k < 10; ++k) gh2v = fmaf(whh2r[k], h2r[k], gh2v);

                float a2   = gi2v + gh2v;
                float a10  = __shfl(a2,   lane + 10);
                float ginv = __shfl(gi2v, lane + 20);
                float ghnv = __shfl(gh2v, lane + 20);
                if (lane < 10) {
                    float r = sigmoidf_(a2);
                    float u = sigmoidf_(a10);
                    float n = tanhf_(fmaf(r, ghnv, ginv));
                    float h2n = fmaf(u, h2own - n, n);
                    sh2ring[(t + 1) & 3][lane] = h2n;
                }
            }
            if (t >= 1) {
                // emitter for step s = t-1: uses h1(s) and H2(s)
                const int s1 = (t - 1) & 1;
                const int s2 = (t - 1) & 3;
                float4 d0 = *(const float4*)(&sh1ring[s1][0]);
                float4 d1 = *(const float4*)(&sh1ring[s1][4]);
                float d8 = sh1ring[s1][8];
                float d9 = sh1ring[s1][9];
                float4 g0 = *(const float4*)(&sh2ring[s2][0]);
                float4 g1 = *(const float4*)(&sh2ring[s2][4]);
                float g8 = sh2ring[s2][8];
                float g9 = sh2ring[s2][9];
                float hv[10] = {d0.x,d0.y,d0.z,d0.w,d1.x,d1.y,d1.z,d1.w,d8,d9};
                float gv[10] = {g0.x,g0.y,g0.z,g0.w,g1.x,g1.y,g1.z,g1.w,g8,g9};

                float e1v = be1r;
#pragma unroll
                for (int k = 0; k < 10; ++k) e1v = fmaf(we1r[k],      hv[k], e1v);
#pragma unroll
                for (int k = 0; k < 10; ++k) e1v = fmaf(we1r[10 + k], gv[k], e1v);
                e1v = fmaxf(e1v, 0.f);
                if (lane < 20) se1[lane] = e1v;
                __builtin_amdgcn_wave_barrier();

                float er[20];
                {
                    float4 b0 = *(const float4*)(&se1[0]);
                    float4 b1 = *(const float4*)(&se1[4]);
                    float4 b2 = *(const float4*)(&se1[8]);
                    float4 b3 = *(const float4*)(&se1[12]);
                    float4 b4 = *(const float4*)(&se1[16]);
                    er[0]=b0.x; er[1]=b0.y; er[2]=b0.z; er[3]=b0.w;
                    er[4]=b1.x; er[5]=b1.y; er[6]=b1.z; er[7]=b1.w;
                    er[8]=b2.x; er[9]=b2.y; er[10]=b2.z; er[11]=b2.w;
                    er[12]=b3.x; er[13]=b3.y; er[14]=b3.z; er[15]=b3.w;
                    er[16]=b4.x; er[17]=b4.y; er[18]=b4.z; er[19]=b4.w;
                }
                float e2v = be2r;
#pragma unroll
                for (int k = 0; k < 20; ++k) e2v = fmaf(we2r[k], er[k], e2v);
                e2v = fmaxf(e2v, 0.f);
                if (lane < 20) se2[lane] = e2v;
                __builtin_amdgcn_wave_barrier();

                float fr[20];
                {
                    float4 b0 = *(const float4*)(&se2[0]);
                    float4 b1 = *(const float4*)(&se2[4]);
                    float4 b2 = *(const float4*)(&se2[8]);
                    float4 b3 = *(const float4*)(&se2[12]);
                    float4 b4 = *(const float4*)(&se2[16]);
                    fr[0]=b0.x; fr[1]=b0.y; fr[2]=b0.z; fr[3]=b0.w;
                    fr[4]=b1.x; fr[5]=b1.y; fr[6]=b1.z; fr[7]=b1.w;
                    fr[8]=b2.x; fr[9]=b2.y; fr[10]=b2.z; fr[11]=b2.w;
                    fr[12]=b3.x; fr[13]=b3.y; fr[14]=b3.z; fr[15]=b3.w;
                    fr[16]=b4.x; fr[17]=b4.y; fr[18]=b4.z; fr[19]=b4.w;
                }
                float xA = be3A, xB = be3B;
#pragma unroll
                for (int l = 0; l < 20; ++l) {
                    xA = fmaf(we3A[l], fr[l], xA);
                    xB = fmaf(we3B[l], fr[l], xB);
                }
                xA = sigmoidf_(xA);
                xB = sigmoidf_(xB);
                if (lane < 50) {
                    int64_t ro = rowbase + (int64_t)(t - 1) * 100;
                    out[ro + lane]      = xA;
                    out[ro + lane + 50] = xB;
                }
            }
            __syncthreads();
        }
    }
}

extern "C" void kernel_launch(void* const* d_in, const int* in_sizes, int n_in,
                              void* d_out, int out_size, void* d_ws, size_t ws_size,
                              hipStream_t stream) {
    const float* mini_batch = (const float*)d_in[0];
    const float* eps        = (const float*)d_in[1];
    const float* W_ih1      = (const float*)d_in[2];
    const float* W_hh1      = (const float*)d_in[3];
    const float* b_ih1      = (const float*)d_in[4];
    const float* b_hh1      = (const float*)d_in[5];
    const float* W_ih2      = (const float*)d_in[6];
    const float* W_hh2      = (const float*)d_in[7];
    const float* b_ih2      = (const float*)d_in[8];
    const float* b_hh2      = (const float*)d_in[9];
    const float* h1_0       = (const float*)d_in[10];
    const float* h2_0       = (const float*)d_in[11];
    const float* Wt1        = (const float*)d_in[12];
    const float* bt1        = (const float*)d_in[13];
    const float* Wloc       = (const float*)d_in[14];
    const float* bloc       = (const float*)d_in[15];
    const float* Wsc        = (const float*)d_in[16];
    const float* bsc        = (const float*)d_in[17];
    const float* We1        = (const float*)d_in[18];
    const float* be1        = (const float*)d_in[19];
    const float* We2        = (const float*)d_in[20];
    const float* be2        = (const float*)d_in[21];
    const float* We3        = (const float*)d_in[22];
    const float* be3        = (const float*)d_in[23];
    float* out = (float*)d_out;

    // K1: gi2 precompute into out[.., 0:30] (scratch region, overwritten later by K2)
    gi2_kernel<<<(NB * T_LEN) / 64, 256, 0, stream>>>(mini_batch, W_ih2, b_ih2, out);

    // K2: sequential scan, one block per batch element
    scan_kernel<<<NB, 128, 0, stream>>>(eps, W_ih1, W_hh1, b_ih1, b_hh1, W_hh2, b_hh2,
                                        h1_0, h2_0, Wt1, bt1, Wloc, bloc, Wsc, bsc,
                                        We1, be1, We2, be2, We3, be3, out);
}

// Round 2
// 751.596 us; speedup vs baseline: 1.6618x; 1.6618x over previous
//
#include <hip/hip_runtime.h>
#include <cstdint>

#define T_LEN 1000
#define NB    256

__device__ __forceinline__ float rcpf_(float x)     { return __builtin_amdgcn_rcpf(x); }
__device__ __forceinline__ float sigmoidf_(float x) { return rcpf_(1.f + __expf(-x)); }
__device__ __forceinline__ float tanhf_(float x) {
    float e = __expf(2.f * x);
    return 1.f - 2.f * rcpf_(e + 1.f);
}
__device__ __forceinline__ float softplusf_(float x) {
    return fmaxf(x, 0.f) + __logf(1.f + __expf(-fabsf(x)));
}
__device__ __forceinline__ float bcast_(float v, int l) {
    return __uint_as_float(__builtin_amdgcn_readlane(__float_as_uint(v), l));
}

// ---------------- K1: gi2 = mini_batch @ W_ih2^T + b_ih2  -> out[b,t,0:30] (scratch) --------
// 64 rows per block of 256 threads. x staged coalesced into LDS transposed (stride 67:
// conflict-free b32 reads, ~3-way write conflicts). W accessed wave-uniformly -> s_loads.
__global__ __launch_bounds__(256) void gi2_kernel(
    const float* __restrict__ x, const float* __restrict__ W,
    const float* __restrict__ bias, float* __restrict__ out)
{
    __shared__ float xsT[100 * 67];          // xsT[k*67 + r], 26.8 KB

    const int tid = threadIdx.x;
    const int64_t base = (int64_t)blockIdx.x * (64 * 100);
    const float4* gx = (const float4*)(x + base);

#pragma unroll
    for (int it = 0; it < 7; ++it) {
        int i = tid + it * 256;
        if (i < 1600) {
            int r  = i / 25;
            int k4 = i - r * 25;
            float4 v = gx[i];                 // coalesced 16B/lane
            xsT[(4 * k4 + 0) * 67 + r] = v.x;
            xsT[(4 * k4 + 1) * 67 + r] = v.y;
            xsT[(4 * k4 + 2) * 67 + r] = v.z;
            xsT[(4 * k4 + 3) * 67 + r] = v.w;
        }
    }
    __syncthreads();

    const int lane = tid & 63;                               // row within tile
    const int wv   = __builtin_amdgcn_readfirstlane(tid >> 6);
    const int j0   = wv * 8;                                 // 8 output cols per wave

    float acc[8];
#pragma unroll
    for (int jj = 0; jj < 8; ++jj) acc[jj] = 0.f;

    for (int k = 0; k < 100; ++k) {
        float xv = xsT[k * 67 + lane];
#pragma unroll
        for (int jj = 0; jj < 8; ++jj) {
            int j = j0 + jj; j = j > 29 ? 29 : j;            // wave-uniform -> s_load
            acc[jj] = fmaf(xv, W[j * 100 + k], acc[jj]);
        }
    }
    float* orow = out + base + (int64_t)lane * 100;
#pragma unroll
    for (int jj = 0; jj < 8; ++jj) {
        int j = j0 + jj;
        if (j < 30) orow[j] = acc[jj] + bias[j];
    }
}

// ---------------- K2: sequential scan. 1 block / batch element, 2 waves ---------------------
// wave0: h1 critical chain (all small broadcasts via readlane->SGPR; Wloc folded into
//        C = W_ih1@Wloc so only the softplus(sc)*eps term needs the 100-wide LDS handoff).
// wave1: h2 GRU (state in SGPRs) + emitter lagged 1 step + output stores.
__global__ __launch_bounds__(128) void scan_kernel(
    const float* __restrict__ eps,
    const float* __restrict__ W_ih1, const float* __restrict__ W_hh1,
    const float* __restrict__ b_ih1, const float* __restrict__ b_hh1,
    const float* __restrict__ W_hh2, const float* __restrict__ b_hh2,
    const float* __restrict__ h1_0,  const float* __restrict__ h2_0,
    const float* __restrict__ Wt1,   const float* __restrict__ bt1,
    const float* __restrict__ Wloc,  const float* __restrict__ bloc,
    const float* __restrict__ Wsc,   const float* __restrict__ bsc,
    const float* __restrict__ We1,   const float* __restrict__ be1,
    const float* __restrict__ We2,   const float* __restrict__ be2,
    const float* __restrict__ We3,   const float* __restrict__ be3,
    float* out)
{
    __shared__ __align__(16) float ss2[2][52];       // z-tilde halves (pads zeroed)
    __shared__ __align__(16) float sh1ring[2][12];   // h1 after step t -> slot t&1 (w0 -> w1)

    const int lane = threadIdx.x & 63;
    const int64_t rowbase = (int64_t)blockIdx.x * T_LEN * 100;
    const int wave = __builtin_amdgcn_readfirstlane((int)(threadIdx.x >> 6));

    if (wave == 0) {
        // ================= wave0: h1 chain =================
        const int j  = lane & 31;
        const int jc = j < 30 ? j : 29;        // clamped row (garbage lanes unused)
        const int h  = lane >> 5;              // k-half for the 100-deep gi1 reduction
        const int lt = lane < 20 ? lane : 19;
        const int ls = lane < 50 ? lane : 49;

        float wt1r[10], whh1r[10], wscA[20], wscB[20], wbig[52], Cr[20];
#pragma unroll
        for (int k = 0; k < 10; ++k) {
            wt1r[k]  = Wt1[lt * 10 + k];
            whh1r[k] = W_hh1[jc * 10 + k];
        }
        float bt1r  = bt1[lt];
        float bhh1r = b_hh1[jc];
        float br1   = b_ih1[jc];
#pragma unroll
        for (int l = 0; l < 20; ++l) {
            wscA[l] = Wsc[ls * 20 + l];
            wscB[l] = Wsc[(ls + 50) * 20 + l];
        }
        float bscA = bsc[ls], bscB = bsc[ls + 50];
#pragma unroll
        for (int i = 0; i < 50; ++i) wbig[i] = W_ih1[jc * 100 + h * 50 + i];
        wbig[50] = 0.f; wbig[51] = 0.f;

        // one-off fold: Cr[l] = (W_ih1 @ Wloc)[jc][l],  dr = (W_ih1 @ bloc)[jc]
        float dr = 0.f;
#pragma unroll
        for (int l = 0; l < 20; ++l) Cr[l] = 0.f;
        for (int kk = 0; kk < 100; ++kk) {
            float w = W_ih1[jc * 100 + kk];
            dr = fmaf(w, bloc[kk], dr);          // bloc[kk] uniform -> s_load
#pragma unroll
            for (int l = 0; l < 20; ++l) Cr[l] = fmaf(w, Wloc[kk * 20 + l], Cr[l]);
        }

        if (lane < 2) { ss2[0][50 + lane] = 0.f; ss2[1][50 + lane] = 0.f; }

        float h1keep = h1_0[lane < 10 ? lane : 0];   // per-lane own h1[j] (lanes 0..9)
        float sh1_[10];
#pragma unroll
        for (int k = 0; k < 10; ++k) sh1_[k] = h1_0[k];   // uniform -> SGPRs

        const float* erow = eps + rowbase;
        float epsA = erow[ls];
        float epsB = erow[ls + 50];

        for (int t = 0; t <= T_LEN; ++t) {
            if (t < T_LEN) {
                // hid + gh1 from SGPR-resident h1
                float hidv = bt1r, gh1v = bhh1r;
#pragma unroll
                for (int k = 0; k < 10; ++k) {
                    hidv = fmaf(wt1r[k], sh1_[k], hidv);
                    gh1v = fmaf(whh1r[k], sh1_[k], gh1v);
                }
                hidv = fmaxf(hidv, 0.f);

                float sgh[20];
#pragma unroll
                for (int l = 0; l < 20; ++l) sgh[l] = bcast_(hidv, l);

                // sc chains + folded loc term gq
                float scA = bscA, scB = bscB, gq = dr;
#pragma unroll
                for (int l = 0; l < 20; ++l) {
                    scA = fmaf(wscA[l], sgh[l], scA);
                    scB = fmaf(wscB[l], sgh[l], scB);
                    gq  = fmaf(Cr[l],  sgh[l], gq);
                }
                float zA = softplusf_(scA) * epsA;
                float zB = softplusf_(scB) * epsB;
                if (lane < 50) { ss2[0][lane] = zA; ss2[1][lane] = zB; }

                // prefetch eps(t+1) (covered by rest of step + barrier)
                if (t + 1 < T_LEN) {
                    epsA = erow[(t + 1) * 100 + ls];
                    epsB = erow[(t + 1) * 100 + ls + 50];
                }
                __builtin_amdgcn_wave_barrier();

                // gi1 partial: 50-deep dot over own k-half, 4 accumulators
                const float4* sp4 = (const float4*)(&ss2[h][0]);
                float p0 = 0.f, p1 = 0.f, p2 = 0.f, p3 = 0.f;
#pragma unroll
                for (int c = 0; c < 13; ++c) {
                    float4 v = sp4[c];
                    p0 = fmaf(wbig[4 * c + 0], v.x, p0);
                    p1 = fmaf(wbig[4 * c + 1], v.y, p1);
                    p2 = fmaf(wbig[4 * c + 2], v.z, p2);
                    p3 = fmaf(wbig[4 * c + 3], v.w, p3);
                }
                float p = (p0 + p1) + (p2 + p3);
                float gi1v = p + __shfl_xor(p, 32) + br1 + gq;
                float av   = gi1v + gh1v;
                float a10  = __shfl(av,   lane + 10);
                float gin  = __shfl(gi1v, lane + 20);
                float ghn  = __shfl(gh1v, lane + 20);
                if (lane < 10) {
                    float r = sigmoidf_(av);
                    float u = sigmoidf_(a10);
                    float n = tanhf_(fmaf(r, ghn, gin));
                    h1keep = fmaf(u, h1keep - n, n);       // (1-u)*n + u*h1
                    sh1ring[t & 1][lane] = h1keep;          // hand-off to wave1
                }
#pragma unroll
                for (int k = 0; k < 10; ++k) sh1_[k] = bcast_(h1keep, k);
            }
            __syncthreads();
        }
    } else {
        // ================= wave1: h2 chain (SGPR state) + emitter(t-1) =================
        const int lt20 = lane < 20 ? lane : 19;
        const int l30  = lane < 30 ? lane : 29;
        const int ls   = lane < 50 ? lane : 49;

        float whh2r[10];
#pragma unroll
        for (int k = 0; k < 10; ++k) whh2r[k] = W_hh2[l30 * 10 + k];
        float bhh2r = b_hh2[l30];

        float we1r[20], we2r[20], we3A[20], we3B[20];
#pragma unroll
        for (int k = 0; k < 20; ++k) {
            we1r[k] = We1[lt20 * 20 + k];
            we2r[k] = We2[lt20 * 20 + k];
            we3A[k] = We3[ls * 20 + k];
            we3B[k] = We3[(ls + 50) * 20 + k];
        }
        float be1r = be1[lt20], be2r = be2[lt20];
        float be3A = be3[ls],   be3B = be3[ls + 50];

        float h2keep = h2_0[lane < 10 ? lane : 0];
        float g2c[10], g2p[10];                  // H2(t), H2(t-1) as uniforms (SGPRs)
#pragma unroll
        for (int k = 0; k < 10; ++k) { g2c[k] = h2_0[k]; g2p[k] = h2_0[k]; }

        float gi2reg = out[rowbase + l30];       // gi2(0) prefetch (written by K1)

        for (int t = 0; t <= T_LEN; ++t) {
            // early h1(t-1) read for emitter (latency hidden under h2 GRU)
            float4 d0 = make_float4(0.f, 0.f, 0.f, 0.f);
            float4 d1 = d0; float d8 = 0.f, d9 = 0.f;
            if (t >= 1) {
                const int s1 = (t - 1) & 1;
                d0 = *(const float4*)(&sh1ring[s1][0]);
                d1 = *(const float4*)(&sh1ring[s1][4]);
                d8 = sh1ring[s1][8]; d9 = sh1ring[s1][9];
            }

            const bool upd = (t < T_LEN);
            if (upd) {
                float gh2v = bhh2r;
#pragma unroll
                for (int k = 0; k < 10; ++k) gh2v = fmaf(whh2r[k], g2c[k], gh2v);
                float gi2v = gi2reg;
                if (t + 1 < T_LEN)
                    gi2reg = out[rowbase + (int64_t)(t + 1) * 100 + l30];
                float a2  = gi2v + gh2v;
                float a10 = __shfl(a2,   lane + 10);
                float gin = __shfl(gi2v, lane + 20);
                float ghn = __shfl(gh2v, lane + 20);
                if (lane < 10) {
                    float r = sigmoidf_(a2);
                    float u = sigmoidf_(a10);
                    float n = tanhf_(fmaf(r, ghn, gin));
                    h2keep = fmaf(u, h2keep - n, n);       // H2(t+1)
                }
            }

            if (t >= 1) {
                // emitter step s = t-1: h1(s) from LDS, H2(s)=g2p from SGPRs
                float e1v = be1r;
                e1v = fmaf(we1r[0], d0.x, e1v); e1v = fmaf(we1r[1], d0.y, e1v);
                e1v = fmaf(we1r[2], d0.z, e1v); e1v = fmaf(we1r[3], d0.w, e1v);
                e1v = fmaf(we1r[4], d1.x, e1v); e1v = fmaf(we1r[5], d1.y, e1v);
                e1v = fmaf(we1r[6], d1.z, e1v); e1v = fmaf(we1r[7], d1.w, e1v);
                e1v = fmaf(we1r[8], d8,   e1v); e1v = fmaf(we1r[9], d9,   e1v);
#pragma unroll
                for (int k = 0; k < 10; ++k) e1v = fmaf(we1r[10 + k], g2p[k], e1v);
                e1v = fmaxf(e1v, 0.f);

                float se1v[20];
#pragma unroll
                for (int l = 0; l < 20; ++l) se1v[l] = bcast_(e1v, l);

                float e2v = be2r;
#pragma unroll
                for (int k = 0; k < 20; ++k) e2v = fmaf(we2r[k], se1v[k], e2v);
                e2v = fmaxf(e2v, 0.f);

                float se2v[20];
#pragma unroll
                for (int l = 0; l < 20; ++l) se2v[l] = bcast_(e2v, l);

                float xA = be3A, xB = be3B;
#pragma unroll
                for (int l = 0; l < 20; ++l) {
                    xA = fmaf(we3A[l], se2v[l], xA);
                    xB = fmaf(we3B[l], se2v[l], xB);
                }
                xA = sigmoidf_(xA);
                xB = sigmoidf_(xB);
                if (lane < 50) {
                    int64_t ro = rowbase + (int64_t)(t - 1) * 100;
                    out[ro + lane]      = xA;
                    out[ro + lane + 50] = xB;
                }
            }

            if (upd) {
#pragma unroll
                for (int k = 0; k < 10; ++k) g2p[k] = g2c[k];
#pragma unroll
                for (int k = 0; k < 10; ++k) g2c[k] = bcast_(h2keep, k);
            }
            __syncthreads();
        }
    }
}

extern "C" void kernel_launch(void* const* d_in, const int* in_sizes, int n_in,
                              void* d_out, int out_size, void* d_ws, size_t ws_size,
                              hipStream_t stream) {
    const float* mini_batch = (const float*)d_in[0];
    const float* eps        = (const float*)d_in[1];
    const float* W_ih1      = (const float*)d_in[2];
    const float* W_hh1      = (const float*)d_in[3];
    const float* b_ih1      = (const float*)d_in[4];
    const float* b_hh1      = (const float*)d_in[5];
    const float* W_ih2      = (const float*)d_in[6];
    const float* W_hh2      = (const float*)d_in[7];
    const float* b_ih2      = (const float*)d_in[8];
    const float* b_hh2      = (const float*)d_in[9];
    const float* h1_0       = (const float*)d_in[10];
    const float* h2_0       = (const float*)d_in[11];
    const float* Wt1        = (const float*)d_in[12];
    const float* bt1        = (const float*)d_in[13];
    const float* Wloc       = (const float*)d_in[14];
    const float* bloc       = (const float*)d_in[15];
    const float* Wsc        = (const float*)d_in[16];
    const float* bsc        = (const float*)d_in[17];
    const float* We1        = (const float*)d_in[18];
    const float* be1        = (const float*)d_in[19];
    const float* We2        = (const float*)d_in[20];
    const float* be2        = (const float*)d_in[21];
    const float* We3        = (const float*)d_in[22];
    const float* be3        = (const float*)d_in[23];
    float* out = (float*)d_out;

    // K1: gi2 precompute into out[.., 0:30] (scratch region, overwritten later by K2)
    gi2_kernel<<<(NB * T_LEN) / 64, 256, 0, stream>>>(mini_batch, W_ih2, b_ih2, out);

    // K2: sequential scan, one block per batch element
    scan_kernel<<<NB, 128, 0, stream>>>(eps, W_ih1, W_hh1, b_ih1, b_hh1, W_hh2, b_hh2,
                                        h1_0, h2_0, Wt1, bt1, Wloc, bloc, Wsc, bsc,
                                        We1, be1, We2, be2, We3, be3, out);
}